// Round 10
// baseline (167.559 us; speedup 1.0000x reference)
//
#include <hip/hip_runtime.h>
#include <math.h>

#define BATCH 2
#define SEQ   2048
#define DMODEL 1024
#define KDIM  1024
#define NH    16
#define HDIM  64
#define GRP   4
#define NKV   4   // NH / GRP

enum { M_PLAIN = 0, M_QKV = 1 };

// ln(10000)
#define LN_THETA 9.210340371976184f
// 0.03125 * log2(e): Q carries the 1/sqrt(D) scale AND the exp->exp2 conversion
#define QSCALE 0.04508422002778f

typedef short bf8_t __attribute__((ext_vector_type(8)));
typedef float f4_t __attribute__((ext_vector_type(4)));
typedef unsigned short us4_t __attribute__((ext_vector_type(4)));
typedef unsigned short us8_t __attribute__((ext_vector_type(8)));

// ws element offsets (bf16 units) -- Qb/Kb/Vb must stay contiguous in this order
#define QB_OFF 0
#define KB_OFF 4194304
#define VB_OFF (4194304 + 1048576)

__device__ __forceinline__ unsigned short f2bf(float f) {
  unsigned int u = __float_as_uint(f);
  u += 0x7fffu + ((u >> 16) & 1u);   // RNE
  return (unsigned short)(u >> 16);
}

__device__ __forceinline__ float fexp2(float x) {
#if __has_builtin(__builtin_amdgcn_exp2f)
  return __builtin_amdgcn_exp2f(x);
#else
  return exp2f(x);
#endif
}

__device__ __forceinline__ void gload_lds16(const void* g, void* l) {
  typedef __attribute__((address_space(1))) unsigned int gu32;
  typedef __attribute__((address_space(3))) unsigned int lu32;
  __builtin_amdgcn_global_load_lds((const gu32*)g, (lu32*)l, 16, 0, 0);
}

// ---- x fp32 -> bf16, same layout. grid*256*4 elements exactly.
__global__ __launch_bounds__(256) void conv_x(const float* __restrict__ in,
                                              unsigned short* __restrict__ out) {
  const int i = blockIdx.x * 256 + threadIdx.x;
  float4 v = ((const float4*)in)[i];
  us4_t o = {f2bf(v.x), f2bf(v.y), f2bf(v.z), f2bf(v.w)};
  ((us4_t*)out)[i] = o;
}

// ---- all 4 weight transposes in ONE launch (z routes). fp32 [K][N] -> bf16 [N][K].
__global__ __launch_bounds__(256) void convT_all(const float* __restrict__ W0,
                                                 const float* __restrict__ W1,
                                                 const float* __restrict__ W2,
                                                 const float* __restrict__ W3,
                                                 unsigned short* __restrict__ Wqkvt,
                                                 unsigned short* __restrict__ Wot) {
  const float* W; unsigned short* out; int N, rowoff;
  switch (blockIdx.z) {
    case 0: W = W0; out = Wqkvt; N = 1024; rowoff = 0;    break;
    case 1: W = W1; out = Wqkvt; N = 256;  rowoff = 1024; break;
    case 2: W = W2; out = Wqkvt; N = 256;  rowoff = 1280; break;
    default: W = W3; out = Wot;  N = 1024; rowoff = 0;    break;
  }
  const int n0 = blockIdx.x * 64;
  if (n0 >= N) return;
  __shared__ unsigned short T[64][72];
  const int t = threadIdx.x;
  const int k0 = blockIdx.y * 64;
  const int kr = t >> 4, n4 = (t & 15) * 4;
#pragma unroll
  for (int i = 0; i < 4; ++i) {
    const int k = kr + i * 16;
    float4 v = *(const float4*)&W[(size_t)(k0 + k) * N + n0 + n4];
    T[n4 + 0][k] = f2bf(v.x);
    T[n4 + 1][k] = f2bf(v.y);
    T[n4 + 2][k] = f2bf(v.z);
    T[n4 + 3][k] = f2bf(v.w);
  }
  __syncthreads();
#pragma unroll
  for (int i = 0; i < 2; ++i) {
    const int c = t + i * 256;
    const int n = c >> 3, kc = (c & 7) * 8;
    us8_t v = *(const us8_t*)&T[n][kc];
    *(us8_t*)&out[(size_t)(rowoff + n0 + n) * KDIM + k0 + kc] = v;
  }
}

// ---- bf16 MFMA GEMM with COUNTED-VMCNT double buffering (T3+T4 minimum).
// Unchanged from R9 (budget says the pair improved ~3 us vs __syncthreads).
// 128x128 tile, 8 waves (4x2, each 32x64, acc[2][4] no-spill profile),
// BK=64, double-buffered 64 KB LDS, vmcnt(4) in steady state (never 0),
// raw s_barrier + sched_barrier(0) fences, XOR chunk swizzle staging.
// Grid: (x = M/128, y = N/128).
template <int MODE>
__global__ __launch_bounds__(512, 2) void gemm_bf16(const unsigned short* __restrict__ A,
                                                    const unsigned short* __restrict__ Bt,
                                                    void* __restrict__ Cdst_, int N) {
  __shared__ __align__(16) unsigned short As[2 * 8192];   // 32 KB: dbuf x 2 panels of 128x32
  __shared__ __align__(16) unsigned short Bs[2 * 8192];   // 32 KB

  const int tid = threadIdx.x;
  const int lane = tid & 63, quad = lane >> 4, l16 = lane & 15;
  const int w = tid >> 6, wm = w >> 1, wn = w & 1;   // wm 0..3 (32-row strip), wn 0..1 (64-col half)
  const int row0 = blockIdx.x * 128, col0 = blockIdx.y * 128;

  const int m0 = tid >> 2;                        // 0..127: staged A-row / B-col
  const int kc0 = (tid & 3) ^ ((m0 >> 1) & 3);    // XOR chunk swizzle (R1-verified)
  const unsigned short* Ag0 = A + (size_t)(row0 + m0) * KDIM + kc0 * 8;
  const unsigned short* Bg0 = Bt + (size_t)(col0 + m0) * KDIM + kc0 * 8;
  unsigned short* Al0 = &As[tid * 8];   // panel-local slot (tid*8 covers one 128x32 panel)
  unsigned short* Bl0 = &Bs[tid * 8];

  // buffer c at +c*8192; panel kh at +kh*4096.  4 gloads per thread per stage.
#define STAGE_GEMM(c, kk)                                        \
  do {                                                           \
    gload_lds16(Ag0 + (kk),      Al0 + (c) * 8192);              \
    gload_lds16(Ag0 + (kk) + 32, Al0 + (c) * 8192 + 4096);       \
    gload_lds16(Bg0 + (kk),      Bl0 + (c) * 8192);              \
    gload_lds16(Bg0 + (kk) + 32, Bl0 + (c) * 8192 + 4096);       \
  } while (0)

  int aoff[2][2], boff[4][2];
#pragma unroll
  for (int mi = 0; mi < 2; ++mi) {
    const int am = wm * 32 + mi * 16 + l16;
    const int sw = quad ^ ((am >> 1) & 3);
#pragma unroll
    for (int kh = 0; kh < 2; ++kh)
      aoff[mi][kh] = kh * 4096 + (((am << 2) | sw) << 3);
  }
#pragma unroll
  for (int ni = 0; ni < 4; ++ni) {
    const int bn = wn * 64 + ni * 16 + l16;
    const int sw = quad ^ ((bn >> 1) & 3);
#pragma unroll
    for (int kh = 0; kh < 2; ++kh)
      boff[ni][kh] = kh * 4096 + (((bn << 2) | sw) << 3);
  }

  f4_t acc[2][4];
#pragma unroll
  for (int mi = 0; mi < 2; ++mi)
#pragma unroll
    for (int ni = 0; ni < 4; ++ni) acc[mi][ni] = (f4_t){0.f, 0.f, 0.f, 0.f};

  STAGE_GEMM(0, 0);
  int cur = 0;
  for (int kb = 0; kb < KDIM; kb += 64) {
    if (kb + 64 < KDIM) {
      STAGE_GEMM(cur ^ 1, kb + 64);                       // 4 new loads in flight
      asm volatile("s_waitcnt vmcnt(4)" ::: "memory");    // buf[cur]'s 4 loads done
    } else {
      asm volatile("s_waitcnt vmcnt(0)" ::: "memory");    // tail: drain
    }
    __builtin_amdgcn_sched_barrier(0);
    __builtin_amdgcn_s_barrier();                         // all waves' buf[cur] staged

    const unsigned short* Asc = As + cur * 8192;
    const unsigned short* Bsc = Bs + cur * 8192;
#pragma unroll
    for (int kh = 0; kh < 2; ++kh) {
      bf8_t af[2], bfr[4];
#pragma unroll
      for (int mi = 0; mi < 2; ++mi) af[mi] = *(const bf8_t*)&Asc[aoff[mi][kh]];
#pragma unroll
      for (int ni = 0; ni < 4; ++ni) bfr[ni] = *(const bf8_t*)&Bsc[boff[ni][kh]];
#pragma unroll
      for (int mi = 0; mi < 2; ++mi)
#pragma unroll
        for (int ni = 0; ni < 4; ++ni)
          acc[mi][ni] = __builtin_amdgcn_mfma_f32_16x16x32_bf16(af[mi], bfr[ni], acc[mi][ni], 0, 0, 0);
    }
    __builtin_amdgcn_sched_barrier(0);
    __builtin_amdgcn_s_barrier();                         // all reads of buf[cur] done
    cur ^= 1;
  }
#undef STAGE_GEMM

  if constexpr (MODE == M_PLAIN) {
    float* out = (float*)Cdst_;
#pragma unroll
    for (int mi = 0; mi < 2; ++mi) {
      const int rowb = row0 + wm * 32 + mi * 16 + quad * 4;
#pragma unroll
      for (int ni = 0; ni < 4; ++ni) {
        const int n = col0 + wn * 64 + ni * 16 + l16;
#pragma unroll
        for (int r = 0; r < 4; ++r)
          out[(size_t)(rowb + r) * N + n] = acc[mi][ni][r];
      }
    }
  } else {  // M_QKV
    unsigned short* Qb = (unsigned short*)Cdst_;
    unsigned short* Kb = Qb + (KB_OFF - QB_OFF);
    unsigned short* Vb = Qb + (VB_OFF - QB_OFF);
#pragma unroll
    for (int ni = 0; ni < 4; ++ni) {
      const int nb = col0 + wn * 64 + ni * 16;   // wave-uniform region selector
      const int n = nb + l16;
      if (nb < 1024) {  // Q + full-D RoPE, scale (1/32)*log2(e) folded -> attn uses exp2
        const float inv = expf(-(float)(2 * (n >> 1)) * (LN_THETA / (float)DMODEL));
        const float sgn = (n & 1) ? 1.f : -1.f;
        const int h = n >> 6, d = n & 63;
#pragma unroll
        for (int mi = 0; mi < 2; ++mi) {
          const int rowb = row0 + wm * 32 + mi * 16 + quad * 4;
#pragma unroll
          for (int r = 0; r < 4; ++r) {
            const int row = rowb + r;
            const int bb = row >> 11, s = row & (SEQ - 1);
            const float v = acc[mi][ni][r];
            const float p = __shfl_xor(v, 1);
            float sn, cs;
            sincosf((float)s * inv, &sn, &cs);
            const float res = (v * cs + sgn * p * sn) * QSCALE;
            Qb[((size_t)(bb * NH + h) * SEQ + s) * HDIM + d] = f2bf(res);
          }
        }
      } else if (nb < 1280) {  // K + per-head RoPE (freqs [0,32))
        const int nk = n - 1024;
        const int hkv = nk >> 6, d = nk & 63;
        const float inv = expf(-(float)(2 * (d >> 1)) * (LN_THETA / (float)DMODEL));
        const float sgn = (nk & 1) ? 1.f : -1.f;
#pragma unroll
        for (int mi = 0; mi < 2; ++mi) {
          const int rowb = row0 + wm * 32 + mi * 16 + quad * 4;
#pragma unroll
          for (int r = 0; r < 4; ++r) {
            const int row = rowb + r;
            const int bb = row >> 11, s = row & (SEQ - 1);
            const float v = acc[mi][ni][r];
            const float p = __shfl_xor(v, 1);
            float sn, cs;
            sincosf((float)s * inv, &sn, &cs);
            const float res = v * cs + sgn * p * sn;
            Kb[((size_t)(bb * NKV + hkv) * SEQ + s) * HDIM + d] = f2bf(res);
          }
        }
      } else {  // V, transposed [B][NKV][HDIM][pkey]: keys PERMUTED within each
                // 64-tile: key (cb,quad_k,r) -> pos (cb>>1)*32+quad_k*8+(cb&1)*4+r
                // (matches attn's register-packed PV k-axis; bit-shuffle below)
        const int nv = n - 1280;
        const int hkv = nv >> 6, d = nv & 63;
#pragma unroll
        for (int mi = 0; mi < 2; ++mi) {
          const int s0 = row0 + wm * 32 + mi * 16 + quad * 4;
          const int bb = s0 >> 11, sl = s0 & (SEQ - 1);
          const int st = sl & 63;   // low 2 bits are 0
          const int ps = (sl & ~63) | (st & 0x20) | ((st & 0x0C) << 1) | ((st & 0x10) >> 2);
          us4_t stv = {f2bf(acc[mi][ni][0]), f2bf(acc[mi][ni][1]),
                       f2bf(acc[mi][ni][2]), f2bf(acc[mi][ni][3])};
          *(us4_t*)&Vb[((size_t)(bb * NKV + hkv) * HDIM + d) * SEQ + ps] = stv;
        }
      }
    }
  }
}

// ---- MFMA flash attention v9: 64-q blocks for 4 blocks/CU occupancy.
// R9 post-mortem: at 512 blocks (2/CU, 2 waves/SIMD) attn sat at 19%
// occupancy, MfmaUtil 27 + VALU 35, HBM 5% -- latency-bound with too few
// waves to overlap the per-tile barrier drain.  Halving the q-block
// (g-loop 2 -> 1, pure replication; fragment mappings unchanged) doubles
// blocks to 1024 = 4/CU = 4 waves/SIMD.  K/V L2 staging doubles (L2 has
// headroom).  s_setprio REMOVED: R9 measured it at -3.5 us on this
// lockstep structure (T5 regime gate: no wave role-split here).
__global__ __launch_bounds__(256, 4) void attn_fwd(const unsigned short* __restrict__ Q,
                                                   const unsigned short* __restrict__ K,
                                                   const unsigned short* __restrict__ V,
                                                   unsigned short* __restrict__ Ow) {
  __shared__ __align__(16) unsigned short Kt[2 * 4096];  // dbuf x 2 panels [key][d-half], 16 KB
  __shared__ __align__(16) unsigned short Vt[2 * 4096];  // dbuf x 2 panels [d][pkey-half], 16 KB

  const int b = blockIdx.x >> 4;
  const int h = blockIdx.x & (NH - 1);
  const int hkv = h >> 2;
  const int q0 = blockIdx.y * 64;
  const int tid = threadIdx.x;
  const int w = tid >> 6;
  const int lane = tid & 63;
  const int quad = lane >> 4;
  const int l16 = lane & 15;

  const unsigned short* Qg = Q + ((size_t)(b * NH + h) * SEQ + q0 + w * 16) * HDIM;
  const unsigned short* Kg = K + (size_t)(b * NKV + hkv) * SEQ * HDIM;
  const unsigned short* Vg = V + (size_t)(b * NKV + hkv) * HDIM * SEQ;

  // Q as B-fragments: lane(q=l16, quad) holds Q[q][d=half*32+quad*8+j]
  bf8_t qb[2];
#pragma unroll
  for (int half = 0; half < 2; ++half)
    qb[half] = *(const bf8_t*)(Qg + (size_t)l16 * HDIM + half * 32 + quad * 8);

  f4_t accO[4];
#pragma unroll
  for (int d = 0; d < 4; ++d) accO[d] = (f4_t){0.f, 0.f, 0.f, 0.f};
  float accLs = 0.f;

  // fragment slot swizzle (row = cb*16+l16 or db*16+l16; (row>>1)&3 = (l16>>1)&3)
  const int sw8 = (quad ^ ((l16 >> 1) & 3)) << 3;   // element offset of 16B slot

  // staging: thread t -> row t>>2, slot t&3, global chunk (t&3)^((row>>1)&3)
  const int skey = tid >> 2;
  const int gc = ((tid & 3) ^ ((tid >> 3) & 3)) << 3;
  const unsigned short* KgA = Kg + (size_t)skey * HDIM + gc;
  const unsigned short* VgA = Vg + (size_t)skey * SEQ + gc;

#define STAGE_ATTN(c, kk)                                                          \
  do {                                                                             \
    gload_lds16(KgA + (size_t)(kk) * HDIM,      &Kt[(c) * 4096 + tid * 8]);        \
    gload_lds16(KgA + (size_t)(kk) * HDIM + 32, &Kt[(c) * 4096 + tid * 8 + 2048]); \
    gload_lds16(VgA + (kk),      &Vt[(c) * 4096 + tid * 8]);                       \
    gload_lds16(VgA + (kk) + 32, &Vt[(c) * 4096 + tid * 8 + 2048]);                \
  } while (0)

  STAGE_ATTN(0, 0);
  __syncthreads();
  int cur = 0;
  for (int k0 = 0; k0 < SEQ; k0 += 64) {
    if (k0 + 64 < SEQ) STAGE_ATTN(cur ^ 1, k0 + 64);   // prefetch next tile

    const unsigned short* Ktc = Kt + cur * 4096;
    const unsigned short* Vtc = Vt + cur * 4096;

    // S^T = K Q^T per 16-key block; P = exp2(S^T) packed straight into
    // PV A-fragments (permuted k-axis; v_cvt_pk_bf16_f32)
    union { bf8_t bf; unsigned int dw[4]; } pa[2];
#pragma unroll
    for (int cb = 0; cb < 4; ++cb) {
      const int koff = (cb * 16 + l16) * 32 + sw8;
      bf8_t kf0 = *(const bf8_t*)&Ktc[koff];
      bf8_t kf1 = *(const bf8_t*)&Ktc[koff + 2048];
      f4_t s = (f4_t){0.f, 0.f, 0.f, 0.f};
      s = __builtin_amdgcn_mfma_f32_16x16x32_bf16(kf0, qb[0], s, 0, 0, 0);
      s = __builtin_amdgcn_mfma_f32_16x16x32_bf16(kf1, qb[1], s, 0, 0, 0);
      const float p0 = fexp2(s[0]), p1 = fexp2(s[1]);
      const float p2 = fexp2(s[2]), p3 = fexp2(s[3]);
      accLs += (p0 + p1) + (p2 + p3);
      unsigned int w0, w1;
      asm("v_cvt_pk_bf16_f32 %0, %1, %2" : "=v"(w0) : "v"(p0), "v"(p1));
      asm("v_cvt_pk_bf16_f32 %0, %1, %2" : "=v"(w1) : "v"(p2), "v"(p3));
      pa[cb >> 1].dw[(cb & 1) * 2 + 0] = w0;
      pa[cb >> 1].dw[(cb & 1) * 2 + 1] = w1;
    }

    // O += P V ; V B-frag = one b128 (permuted global key order matches pa)
#pragma unroll
    for (int db = 0; db < 4; ++db) {
      const int voff = (db * 16 + l16) * 32 + sw8;
      bf8_t vf0 = *(const bf8_t*)&Vtc[voff];
      bf8_t vf1 = *(const bf8_t*)&Vtc[voff + 2048];
      accO[db] = __builtin_amdgcn_mfma_f32_16x16x32_bf16(pa[0].bf, vf0, accO[db], 0, 0, 0);
      accO[db] = __builtin_amdgcn_mfma_f32_16x16x32_bf16(pa[1].bf, vf1, accO[db], 0, 0, 0);
    }

    __syncthreads();   // drains prefetch vmcnt AFTER compute (latency hidden)
    cur ^= 1;
  }
#undef STAGE_ATTN

  // L: per-lane partials cover keys {quad*4+r} for q=l16 -> reduce across
  // quads; after the xor-reduce every lane holds the FULL L for q = l16.
  accLs += __shfl_xor(accLs, 16);
  accLs += __shfl_xor(accLs, 32);
  const float il = 1.0f / accLs;

  // write normalized bf16 straight into Owb[b*SEQ+q][h*64+d]
#pragma unroll
  for (int r = 0; r < 4; ++r) {
    // L-reciprocal for this fragment row (q-row quad*4+r) lives at lane l16=quad*4+r
    const float ilr = __shfl(il, quad * 4 + r);
    const int q = q0 + w * 16 + quad * 4 + r;
    unsigned short* op = Ow + (((size_t)b * SEQ + q) * NH + h) * HDIM;
#pragma unroll
    for (int db = 0; db < 4; ++db)
      op[db * 16 + l16] = f2bf(accO[db][r] * ilr);
  }
}

extern "C" void kernel_launch(void* const* d_in, const int* in_sizes, int n_in,
                              void* d_out, int out_size, void* d_ws, size_t ws_size,
                              hipStream_t stream) {
  (void)in_sizes; (void)n_in; (void)out_size; (void)ws_size;
  const float* x  = (const float*)d_in[0];
  const float* Wq = (const float*)d_in[1];
  const float* Wk = (const float*)d_in[2];
  const float* Wv = (const float*)d_in[3];
  const float* Wo = (const float*)d_in[4];
  float* out = (float*)d_out;

  // ws layout (bf16 units).
  unsigned short* Qb    = (unsigned short*)d_ws;          // 4194304
  unsigned short* Kb    = Qb + 4194304;                   // 1048576
  unsigned short* Vb    = Kb + 1048576;                   // 1048576
  unsigned short* Owb   = Vb + 1048576;                   // 4194304
  unsigned short* xb    = Owb + 4194304;                  // 4194304
  unsigned short* Wqkvt = xb + 4194304;                   // 1572864 (Q|K|V rows)
  unsigned short* Wot   = Wqkvt + 1572864;                // 1048576

  dim3 blk(256);
  conv_x<<<dim3(4096), blk, 0, stream>>>(x, xb);
  convT_all<<<dim3(16, 16, 4), blk, 0, stream>>>(Wq, Wk, Wv, Wo, Wqkvt, Wot);

  gemm_bf16<M_QKV><<<dim3(32, 12), dim3(512), 0, stream>>>(xb, Wqkvt, Qb, 1536);
  attn_fwd<<<dim3(BATCH * NH, SEQ / 64), blk, 0, stream>>>(Qb, Kb, Vb, Owb);
  gemm_bf16<M_PLAIN><<<dim3(32, 8), dim3(512), 0, stream>>>(Owb, Wot, out, DMODEL);
}

// Round 11
// 162.941 us; speedup vs baseline: 1.0283x; 1.0283x over previous
//
#include <hip/hip_runtime.h>
#include <math.h>

#define BATCH 2
#define SEQ   2048
#define DMODEL 1024
#define KDIM  1024
#define NH    16
#define HDIM  64
#define GRP   4
#define NKV   4   // NH / GRP

enum { M_PLAIN = 0, M_QKV = 1 };

// ln(10000)
#define LN_THETA 9.210340371976184f
// 0.03125 * log2(e): Q carries the 1/sqrt(D) scale AND the exp->exp2 conversion
#define QSCALE 0.04508422002778f

typedef short bf8_t __attribute__((ext_vector_type(8)));
typedef float f4_t __attribute__((ext_vector_type(4)));
typedef unsigned short us4_t __attribute__((ext_vector_type(4)));
typedef unsigned short us8_t __attribute__((ext_vector_type(8)));

// ws element offsets (bf16 units) -- Qb/Kb/Vb must stay contiguous in this order
#define QB_OFF 0
#define KB_OFF 4194304
#define VB_OFF (4194304 + 1048576)

__device__ __forceinline__ unsigned short f2bf(float f) {
  unsigned int u = __float_as_uint(f);
  u += 0x7fffu + ((u >> 16) & 1u);   // RNE
  return (unsigned short)(u >> 16);
}

__device__ __forceinline__ float fexp2(float x) {
#if __has_builtin(__builtin_amdgcn_exp2f)
  return __builtin_amdgcn_exp2f(x);
#else
  return exp2f(x);
#endif
}

__device__ __forceinline__ void gload_lds16(const void* g, void* l) {
  typedef __attribute__((address_space(1))) unsigned int gu32;
  typedef __attribute__((address_space(3))) unsigned int lu32;
  __builtin_amdgcn_global_load_lds((const gu32*)g, (lu32*)l, 16, 0, 0);
}

// ---- x fp32 -> bf16, same layout. grid*256*4 elements exactly.
__global__ __launch_bounds__(256) void conv_x(const float* __restrict__ in,
                                              unsigned short* __restrict__ out) {
  const int i = blockIdx.x * 256 + threadIdx.x;
  float4 v = ((const float4*)in)[i];
  us4_t o = {f2bf(v.x), f2bf(v.y), f2bf(v.z), f2bf(v.w)};
  ((us4_t*)out)[i] = o;
}

// ---- all 4 weight transposes in ONE launch (z routes). fp32 [K][N] -> bf16 [N][K].
__global__ __launch_bounds__(256) void convT_all(const float* __restrict__ W0,
                                                 const float* __restrict__ W1,
                                                 const float* __restrict__ W2,
                                                 const float* __restrict__ W3,
                                                 unsigned short* __restrict__ Wqkvt,
                                                 unsigned short* __restrict__ Wot) {
  const float* W; unsigned short* out; int N, rowoff;
  switch (blockIdx.z) {
    case 0: W = W0; out = Wqkvt; N = 1024; rowoff = 0;    break;
    case 1: W = W1; out = Wqkvt; N = 256;  rowoff = 1024; break;
    case 2: W = W2; out = Wqkvt; N = 256;  rowoff = 1280; break;
    default: W = W3; out = Wot;  N = 1024; rowoff = 0;    break;
  }
  const int n0 = blockIdx.x * 64;
  if (n0 >= N) return;
  __shared__ unsigned short T[64][72];
  const int t = threadIdx.x;
  const int k0 = blockIdx.y * 64;
  const int kr = t >> 4, n4 = (t & 15) * 4;
#pragma unroll
  for (int i = 0; i < 4; ++i) {
    const int k = kr + i * 16;
    float4 v = *(const float4*)&W[(size_t)(k0 + k) * N + n0 + n4];
    T[n4 + 0][k] = f2bf(v.x);
    T[n4 + 1][k] = f2bf(v.y);
    T[n4 + 2][k] = f2bf(v.z);
    T[n4 + 3][k] = f2bf(v.w);
  }
  __syncthreads();
#pragma unroll
  for (int i = 0; i < 2; ++i) {
    const int c = t + i * 256;
    const int n = c >> 3, kc = (c & 7) * 8;
    us8_t v = *(const us8_t*)&T[n][kc];
    *(us8_t*)&out[(size_t)(rowoff + n0 + n) * KDIM + k0 + kc] = v;
  }
}

// ---- bf16 MFMA GEMM with COUNTED-VMCNT double buffering (T3+T4 minimum;
// R9-verified ~7us win on the pair vs __syncthreads).  128x128 tile, 8
// waves (4x2, each 32x64, acc[2][4] no-spill profile), BK=64, dbuf 64 KB
// LDS, vmcnt(4) steady state, raw s_barrier + sched_barrier(0) fences,
// XOR chunk swizzle staging.
// NEW: XCD-aware block swizzle (T1).  Linear bid (x-fast dispatch) round-
// robins XCDs; remap so XCD k = bid%8 gets a CONTIGUOUS chunk of the block
// space -> its ~1.5 B-panel columns stay resident in that XCD's L2.
// Bijective: both grids (384, 256) are %8==0.
template <int MODE>
__global__ __launch_bounds__(512, 2) void gemm_bf16(const unsigned short* __restrict__ A,
                                                    const unsigned short* __restrict__ Bt,
                                                    void* __restrict__ Cdst_, int N) {
  __shared__ __align__(16) unsigned short As[2 * 8192];   // 32 KB: dbuf x 2 panels of 128x32
  __shared__ __align__(16) unsigned short Bs[2 * 8192];   // 32 KB

  const int tid = threadIdx.x;
  const int lane = tid & 63, quad = lane >> 4, l16 = lane & 15;
  const int w = tid >> 6, wm = w >> 1, wn = w & 1;   // wm 0..3 (32-row strip), wn 0..1 (64-col half)

  // XCD swizzle: gridDim.x == 32 for both modes.
  const int nwg = gridDim.x * gridDim.y;
  const int bid = blockIdx.x + (blockIdx.y << 5);
  const int swz = (bid & 7) * (nwg >> 3) + (bid >> 3);
  const int row0 = (swz & 31) * 128, col0 = (swz >> 5) * 128;

  const int m0 = tid >> 2;                        // 0..127: staged A-row / B-col
  const int kc0 = (tid & 3) ^ ((m0 >> 1) & 3);    // XOR chunk swizzle (R1-verified)
  const unsigned short* Ag0 = A + (size_t)(row0 + m0) * KDIM + kc0 * 8;
  const unsigned short* Bg0 = Bt + (size_t)(col0 + m0) * KDIM + kc0 * 8;
  unsigned short* Al0 = &As[tid * 8];   // panel-local slot (tid*8 covers one 128x32 panel)
  unsigned short* Bl0 = &Bs[tid * 8];

  // buffer c at +c*8192; panel kh at +kh*4096.  4 gloads per thread per stage.
#define STAGE_GEMM(c, kk)                                        \
  do {                                                           \
    gload_lds16(Ag0 + (kk),      Al0 + (c) * 8192);              \
    gload_lds16(Ag0 + (kk) + 32, Al0 + (c) * 8192 + 4096);       \
    gload_lds16(Bg0 + (kk),      Bl0 + (c) * 8192);              \
    gload_lds16(Bg0 + (kk) + 32, Bl0 + (c) * 8192 + 4096);       \
  } while (0)

  int aoff[2][2], boff[4][2];
#pragma unroll
  for (int mi = 0; mi < 2; ++mi) {
    const int am = wm * 32 + mi * 16 + l16;
    const int sw = quad ^ ((am >> 1) & 3);
#pragma unroll
    for (int kh = 0; kh < 2; ++kh)
      aoff[mi][kh] = kh * 4096 + (((am << 2) | sw) << 3);
  }
#pragma unroll
  for (int ni = 0; ni < 4; ++ni) {
    const int bn = wn * 64 + ni * 16 + l16;
    const int sw = quad ^ ((bn >> 1) & 3);
#pragma unroll
    for (int kh = 0; kh < 2; ++kh)
      boff[ni][kh] = kh * 4096 + (((bn << 2) | sw) << 3);
  }

  f4_t acc[2][4];
#pragma unroll
  for (int mi = 0; mi < 2; ++mi)
#pragma unroll
    for (int ni = 0; ni < 4; ++ni) acc[mi][ni] = (f4_t){0.f, 0.f, 0.f, 0.f};

  STAGE_GEMM(0, 0);
  int cur = 0;
  for (int kb = 0; kb < KDIM; kb += 64) {
    if (kb + 64 < KDIM) {
      STAGE_GEMM(cur ^ 1, kb + 64);                       // 4 new loads in flight
      asm volatile("s_waitcnt vmcnt(4)" ::: "memory");    // buf[cur]'s 4 loads done
    } else {
      asm volatile("s_waitcnt vmcnt(0)" ::: "memory");    // tail: drain
    }
    __builtin_amdgcn_sched_barrier(0);
    __builtin_amdgcn_s_barrier();                         // all waves' buf[cur] staged

    const unsigned short* Asc = As + cur * 8192;
    const unsigned short* Bsc = Bs + cur * 8192;
#pragma unroll
    for (int kh = 0; kh < 2; ++kh) {
      bf8_t af[2], bfr[4];
#pragma unroll
      for (int mi = 0; mi < 2; ++mi) af[mi] = *(const bf8_t*)&Asc[aoff[mi][kh]];
#pragma unroll
      for (int ni = 0; ni < 4; ++ni) bfr[ni] = *(const bf8_t*)&Bsc[boff[ni][kh]];
#pragma unroll
      for (int mi = 0; mi < 2; ++mi)
#pragma unroll
        for (int ni = 0; ni < 4; ++ni)
          acc[mi][ni] = __builtin_amdgcn_mfma_f32_16x16x32_bf16(af[mi], bfr[ni], acc[mi][ni], 0, 0, 0);
    }
    __builtin_amdgcn_sched_barrier(0);
    __builtin_amdgcn_s_barrier();                         // all reads of buf[cur] done
    cur ^= 1;
  }
#undef STAGE_GEMM

  if constexpr (MODE == M_PLAIN) {
    float* out = (float*)Cdst_;
#pragma unroll
    for (int mi = 0; mi < 2; ++mi) {
      const int rowb = row0 + wm * 32 + mi * 16 + quad * 4;
#pragma unroll
      for (int ni = 0; ni < 4; ++ni) {
        const int n = col0 + wn * 64 + ni * 16 + l16;
#pragma unroll
        for (int r = 0; r < 4; ++r)
          out[(size_t)(rowb + r) * N + n] = acc[mi][ni][r];
      }
    }
  } else {  // M_QKV
    unsigned short* Qb = (unsigned short*)Cdst_;
    unsigned short* Kb = Qb + (KB_OFF - QB_OFF);
    unsigned short* Vb = Qb + (VB_OFF - QB_OFF);
#pragma unroll
    for (int ni = 0; ni < 4; ++ni) {
      const int nb = col0 + wn * 64 + ni * 16;   // wave-uniform region selector
      const int n = nb + l16;
      if (nb < 1024) {  // Q + full-D RoPE, scale (1/32)*log2(e) folded -> attn uses exp2
        const float inv = expf(-(float)(2 * (n >> 1)) * (LN_THETA / (float)DMODEL));
        const float sgn = (n & 1) ? 1.f : -1.f;
        const int h = n >> 6, d = n & 63;
#pragma unroll
        for (int mi = 0; mi < 2; ++mi) {
          const int rowb = row0 + wm * 32 + mi * 16 + quad * 4;
#pragma unroll
          for (int r = 0; r < 4; ++r) {
            const int row = rowb + r;
            const int bb = row >> 11, s = row & (SEQ - 1);
            const float v = acc[mi][ni][r];
            const float p = __shfl_xor(v, 1);
            float sn, cs;
            sincosf((float)s * inv, &sn, &cs);
            const float res = (v * cs + sgn * p * sn) * QSCALE;
            Qb[((size_t)(bb * NH + h) * SEQ + s) * HDIM + d] = f2bf(res);
          }
        }
      } else if (nb < 1280) {  // K + per-head RoPE (freqs [0,32))
        const int nk = n - 1024;
        const int hkv = nk >> 6, d = nk & 63;
        const float inv = expf(-(float)(2 * (d >> 1)) * (LN_THETA / (float)DMODEL));
        const float sgn = (nk & 1) ? 1.f : -1.f;
#pragma unroll
        for (int mi = 0; mi < 2; ++mi) {
          const int rowb = row0 + wm * 32 + mi * 16 + quad * 4;
#pragma unroll
          for (int r = 0; r < 4; ++r) {
            const int row = rowb + r;
            const int bb = row >> 11, s = row & (SEQ - 1);
            const float v = acc[mi][ni][r];
            const float p = __shfl_xor(v, 1);
            float sn, cs;
            sincosf((float)s * inv, &sn, &cs);
            const float res = v * cs + sgn * p * sn;
            Kb[((size_t)(bb * NKV + hkv) * SEQ + s) * HDIM + d] = f2bf(res);
          }
        }
      } else {  // V, transposed [B][NKV][HDIM][pkey]: keys PERMUTED within each
                // 64-tile: key (cb,quad_k,r) -> pos (cb>>1)*32+quad_k*8+(cb&1)*4+r
                // (matches attn's register-packed PV k-axis; bit-shuffle below)
        const int nv = n - 1280;
        const int hkv = nv >> 6, d = nv & 63;
#pragma unroll
        for (int mi = 0; mi < 2; ++mi) {
          const int s0 = row0 + wm * 32 + mi * 16 + quad * 4;
          const int bb = s0 >> 11, sl = s0 & (SEQ - 1);
          const int st = sl & 63;   // low 2 bits are 0
          const int ps = (sl & ~63) | (st & 0x20) | ((st & 0x0C) << 1) | ((st & 0x10) >> 2);
          us4_t stv = {f2bf(acc[mi][ni][0]), f2bf(acc[mi][ni][1]),
                       f2bf(acc[mi][ni][2]), f2bf(acc[mi][ni][3])};
          *(us4_t*)&Vb[((size_t)(bb * NKV + hkv) * HDIM + d) * SEQ + ps] = stv;
        }
      }
    }
  }
}

// ---- MFMA flash attention v10 = R8's proven-best v8 (128-q blocks, 4
// waves x 32q, g=2, NO setprio) + XCD-group block swizzle: XCD k = bid%8
// (round-robin dispatch) gets all 64 blocks of one (b,hkv) group, whose
// K+V total only 512 KB -> resident in that XCD's private L2 after first
// touch (vs interleaved dispatch bouncing K/V staging off L3).
// R9 lesson: setprio -3.5us on this lockstep structure (T5 regime gate).
// R10 lesson: 64-q blocks -7% (staging/barrier overhead doubles).
__global__ __launch_bounds__(256, 4) void attn_fwd(const unsigned short* __restrict__ Q,
                                                   const unsigned short* __restrict__ K,
                                                   const unsigned short* __restrict__ V,
                                                   unsigned short* __restrict__ Ow) {
  __shared__ __align__(16) unsigned short Kt[2 * 4096];  // dbuf x 2 panels [key][d-half], 16 KB
  __shared__ __align__(16) unsigned short Vt[2 * 4096];  // dbuf x 2 panels [d][pkey-half], 16 KB

  // XCD-group swizzle (bijective: 512 blocks, 8 groups of 64).
  const int bid = blockIdx.x + (blockIdx.y << 5);   // x-fast linear dispatch id
  const int grp = bid & 7;                          // -> XCD under round-robin
  const int idx = bid >> 3;                         // 0..63 within group
  const int b   = grp >> 2;
  const int hkv = grp & 3;
  const int h   = hkv * 4 + (idx & 3);
  const int q0  = (idx >> 2) * 128;

  const int tid = threadIdx.x;
  const int w = tid >> 6;
  const int lane = tid & 63;
  const int quad = lane >> 4;
  const int l16 = lane & 15;

  const unsigned short* Qg = Q + ((size_t)(b * NH + h) * SEQ + q0 + w * 32) * HDIM;
  const unsigned short* Kg = K + (size_t)(b * NKV + hkv) * SEQ * HDIM;
  const unsigned short* Vg = V + (size_t)(b * NKV + hkv) * HDIM * SEQ;

  // Q as B-fragments: lane(n=l16 -> q, quad) holds Q[q][d=half*32+quad*8+j]
  bf8_t qb[2][2];
#pragma unroll
  for (int g = 0; g < 2; ++g)
#pragma unroll
    for (int half = 0; half < 2; ++half)
      qb[g][half] = *(const bf8_t*)(Qg + (size_t)(g * 16 + l16) * HDIM + half * 32 + quad * 8);

  f4_t accO[2][4];
#pragma unroll
  for (int g = 0; g < 2; ++g)
#pragma unroll
    for (int d = 0; d < 4; ++d) accO[g][d] = (f4_t){0.f, 0.f, 0.f, 0.f};
  float accLs[2] = {0.f, 0.f};

  // fragment slot swizzle (row = cb*16+l16 or db*16+l16; (row>>1)&3 = (l16>>1)&3)
  const int sw8 = (quad ^ ((l16 >> 1) & 3)) << 3;   // element offset of 16B slot

  // staging: thread t -> row t>>2, slot t&3, global chunk (t&3)^((row>>1)&3)
  const int skey = tid >> 2;
  const int gc = ((tid & 3) ^ ((tid >> 3) & 3)) << 3;
  const unsigned short* KgA = Kg + (size_t)skey * HDIM + gc;
  const unsigned short* VgA = Vg + (size_t)skey * SEQ + gc;

#define STAGE_ATTN(c, kk)                                                          \
  do {                                                                             \
    gload_lds16(KgA + (size_t)(kk) * HDIM,      &Kt[(c) * 4096 + tid * 8]);        \
    gload_lds16(KgA + (size_t)(kk) * HDIM + 32, &Kt[(c) * 4096 + tid * 8 + 2048]); \
    gload_lds16(VgA + (kk),      &Vt[(c) * 4096 + tid * 8]);                       \
    gload_lds16(VgA + (kk) + 32, &Vt[(c) * 4096 + tid * 8 + 2048]);                \
  } while (0)

  STAGE_ATTN(0, 0);
  __syncthreads();
  int cur = 0;
  for (int k0 = 0; k0 < SEQ; k0 += 64) {
    if (k0 + 64 < SEQ) STAGE_ATTN(cur ^ 1, k0 + 64);   // prefetch next tile

    const unsigned short* Ktc = Kt + cur * 4096;
    const unsigned short* Vtc = Vt + cur * 4096;

    // S^T = K Q^T per 16-key block; P = exp2(S^T) packed straight into
    // PV A-fragments (permuted k-axis; v_cvt_pk_bf16_f32)
    union { bf8_t bf; unsigned int dw[4]; } pa[2][2];
#pragma unroll
    for (int cb = 0; cb < 4; ++cb) {
      const int koff = (cb * 16 + l16) * 32 + sw8;
      bf8_t kf0 = *(const bf8_t*)&Ktc[koff];
      bf8_t kf1 = *(const bf8_t*)&Ktc[koff + 2048];
#pragma unroll
      for (int g = 0; g < 2; ++g) {
        f4_t s = (f4_t){0.f, 0.f, 0.f, 0.f};
        s = __builtin_amdgcn_mfma_f32_16x16x32_bf16(kf0, qb[g][0], s, 0, 0, 0);
        s = __builtin_amdgcn_mfma_f32_16x16x32_bf16(kf1, qb[g][1], s, 0, 0, 0);
        const float p0 = fexp2(s[0]), p1 = fexp2(s[1]);
        const float p2 = fexp2(s[2]), p3 = fexp2(s[3]);
        accLs[g] += (p0 + p1) + (p2 + p3);
        unsigned int w0, w1;
        asm("v_cvt_pk_bf16_f32 %0, %1, %2" : "=v"(w0) : "v"(p0), "v"(p1));
        asm("v_cvt_pk_bf16_f32 %0, %1, %2" : "=v"(w1) : "v"(p2), "v"(p3));
        pa[g][cb >> 1].dw[(cb & 1) * 2 + 0] = w0;
        pa[g][cb >> 1].dw[(cb & 1) * 2 + 1] = w1;
      }
    }

    // O += P V ; V B-frag = one b128 (permuted global key order matches pa)
#pragma unroll
    for (int db = 0; db < 4; ++db) {
      const int voff = (db * 16 + l16) * 32 + sw8;
      bf8_t vf0 = *(const bf8_t*)&Vtc[voff];
      bf8_t vf1 = *(const bf8_t*)&Vtc[voff + 2048];
#pragma unroll
      for (int g = 0; g < 2; ++g) {
        accO[g][db] = __builtin_amdgcn_mfma_f32_16x16x32_bf16(pa[g][0].bf, vf0, accO[g][db], 0, 0, 0);
        accO[g][db] = __builtin_amdgcn_mfma_f32_16x16x32_bf16(pa[g][1].bf, vf1, accO[g][db], 0, 0, 0);
      }
    }

    __syncthreads();   // drains prefetch vmcnt AFTER compute (latency hidden)
    cur ^= 1;
  }
#undef STAGE_ATTN

  // L: per-lane partials cover keys {quad*4+r} for q=l16 -> reduce across quads.
  // After the xor-reduce every lane holds the FULL L for q = g*16 + l16.
#pragma unroll
  for (int g = 0; g < 2; ++g) {
    accLs[g] += __shfl_xor(accLs[g], 16);
    accLs[g] += __shfl_xor(accLs[g], 32);
  }
  const float il0 = 1.0f / accLs[0];
  const float il1 = 1.0f / accLs[1];

  // write normalized bf16 straight into Owb[b*SEQ+q][h*64+d]
#pragma unroll
  for (int g = 0; g < 2; ++g)
#pragma unroll
    for (int r = 0; r < 4; ++r) {
      // L-reciprocal for this fragment row (q-row quad*4+r) lives at lane l16=quad*4+r
      const float ilr = __shfl(g ? il1 : il0, quad * 4 + r);
      const int q = q0 + w * 32 + g * 16 + quad * 4 + r;
      unsigned short* op = Ow + (((size_t)b * SEQ + q) * NH + h) * HDIM;
#pragma unroll
      for (int db = 0; db < 4; ++db)
        op[db * 16 + l16] = f2bf(accO[g][db][r] * ilr);
    }
}

extern "C" void kernel_launch(void* const* d_in, const int* in_sizes, int n_in,
                              void* d_out, int out_size, void* d_ws, size_t ws_size,
                              hipStream_t stream) {
  (void)in_sizes; (void)n_in; (void)out_size; (void)ws_size;
  const float* x  = (const float*)d_in[0];
  const float* Wq = (const float*)d_in[1];
  const float* Wk = (const float*)d_in[2];
  const float* Wv = (const float*)d_in[3];
  const float* Wo = (const float*)d_in[4];
  float* out = (float*)d_out;

  // ws layout (bf16 units).
  unsigned short* Qb    = (unsigned short*)d_ws;          // 4194304
  unsigned short* Kb    = Qb + 4194304;                   // 1048576
  unsigned short* Vb    = Kb + 1048576;                   // 1048576
  unsigned short* Owb   = Vb + 1048576;                   // 4194304
  unsigned short* xb    = Owb + 4194304;                  // 4194304
  unsigned short* Wqkvt = xb + 4194304;                   // 1572864 (Q|K|V rows)
  unsigned short* Wot   = Wqkvt + 1572864;                // 1048576

  dim3 blk(256);
  conv_x<<<dim3(4096), blk, 0, stream>>>(x, xb);
  convT_all<<<dim3(16, 16, 4), blk, 0, stream>>>(Wq, Wk, Wv, Wo, Wqkvt, Wot);

  gemm_bf16<M_QKV><<<dim3(32, 12), dim3(512), 0, stream>>>(xb, Wqkvt, Qb, 1536);
  attn_fwd<<<dim3(32, 16), blk, 0, stream>>>(Qb, Kb, Vb, Owb);
  gemm_bf16<M_PLAIN><<<dim3(32, 8), dim3(512), 0, stream>>>(Owb, Wot, out, DMODEL);
}

// Round 12
// 162.826 us; speedup vs baseline: 1.0291x; 1.0007x over previous
//
#include <hip/hip_runtime.h>
#include <math.h>

#define BATCH 2
#define SEQ   2048
#define DMODEL 1024
#define KDIM  1024
#define NH    16
#define HDIM  64
#define GRP   4
#define NKV   4   // NH / GRP

enum { M_PLAIN = 0, M_QKV = 1 };

// ln(10000)
#define LN_THETA 9.210340371976184f
// 0.03125 * log2(e): Q carries the 1/sqrt(D) scale AND the exp->exp2 conversion
#define QSCALE 0.04508422002778f

typedef short bf8_t __attribute__((ext_vector_type(8)));
typedef float f4_t __attribute__((ext_vector_type(4)));
typedef unsigned short us4_t __attribute__((ext_vector_type(4)));
typedef unsigned short us8_t __attribute__((ext_vector_type(8)));

// ws element offsets (bf16 units) -- Qb/Kb/Vb must stay contiguous in this order
#define QB_OFF 0
#define KB_OFF 4194304
#define VB_OFF (4194304 + 1048576)

__device__ __forceinline__ unsigned short f2bf(float f) {
  unsigned int u = __float_as_uint(f);
  u += 0x7fffu + ((u >> 16) & 1u);   // RNE
  return (unsigned short)(u >> 16);
}

__device__ __forceinline__ float fexp2(float x) {
#if __has_builtin(__builtin_amdgcn_exp2f)
  return __builtin_amdgcn_exp2f(x);
#else
  return exp2f(x);
#endif
}

__device__ __forceinline__ void gload_lds16(const void* g, void* l) {
  typedef __attribute__((address_space(1))) unsigned int gu32;
  typedef __attribute__((address_space(3))) unsigned int lu32;
  __builtin_amdgcn_global_load_lds((const gu32*)g, (lu32*)l, 16, 0, 0);
}

// ---- fused prep: ONE launch does (a) x fp32->bf16, (b) all 4 weight
// transposes, (c) RoPE cos/sin table.  Flat grid of 9216 blocks, ranges
// route.  Rationale: 3 independent memory-light kernels -> fusing removes
// 2 launch gaps and lets them overlap; the table removes 32 sincosf
// (~1000 VALU cyc tail) from EVERY gemm_QKV thread's epilogue (Appendix B:
// on-device trig for RoPE turns memory-bound into VALU-bound).
// tab[(s<<9)|j] = {cos(s*inv_j), sin(s*inv_j)}, inv_j = theta^(-2j/D);
// Q uses j = n>>1 (j<512), K uses j = d>>1 (j<32) -- one table covers both.
__global__ __launch_bounds__(256) void prep(const float* __restrict__ x,
                                            const float* __restrict__ W0,
                                            const float* __restrict__ W1,
                                            const float* __restrict__ W2,
                                            const float* __restrict__ W3,
                                            unsigned short* __restrict__ xb,
                                            unsigned short* __restrict__ Wqkvt,
                                            unsigned short* __restrict__ Wot,
                                            float2* __restrict__ tab) {
  __shared__ unsigned short T[64][72];
  const int blk = blockIdx.x;
  const int t = threadIdx.x;

  if (blk < 4096) {            // ---- conv_x: 4096 blocks
    const int i = blk * 256 + t;
    float4 v = ((const float4*)x)[i];
    us4_t o = {f2bf(v.x), f2bf(v.y), f2bf(v.z), f2bf(v.w)};
    ((us4_t*)xb)[i] = o;
  } else if (blk < 5120) {     // ---- convT_all: 1024 blocks (16 x 16 x 4)
    const int flat = blk - 4096;
    const int bx = flat & 15, by = (flat >> 4) & 15, bz = flat >> 8;
    const float* W; unsigned short* out; int N, rowoff;
    switch (bz) {
      case 0: W = W0; out = Wqkvt; N = 1024; rowoff = 0;    break;
      case 1: W = W1; out = Wqkvt; N = 256;  rowoff = 1024; break;
      case 2: W = W2; out = Wqkvt; N = 256;  rowoff = 1280; break;
      default: W = W3; out = Wot;  N = 1024; rowoff = 0;    break;
    }
    const int n0 = bx * 64;
    if (n0 >= N) return;
    const int k0 = by * 64;
    const int kr = t >> 4, n4 = (t & 15) * 4;
#pragma unroll
    for (int i = 0; i < 4; ++i) {
      const int k = kr + i * 16;
      float4 v = *(const float4*)&W[(size_t)(k0 + k) * N + n0 + n4];
      T[n4 + 0][k] = f2bf(v.x);
      T[n4 + 1][k] = f2bf(v.y);
      T[n4 + 2][k] = f2bf(v.z);
      T[n4 + 3][k] = f2bf(v.w);
    }
    __syncthreads();
#pragma unroll
    for (int i = 0; i < 2; ++i) {
      const int c = t + i * 256;
      const int n = c >> 3, kc = (c & 7) * 8;
      us8_t v = *(const us8_t*)&T[n][kc];
      *(us8_t*)&out[(size_t)(rowoff + n0 + n) * KDIM + k0 + kc] = v;
    }
  } else {                     // ---- RoPE table: 4096 blocks, 1M entries
    const int i = (blk - 5120) * 256 + t;     // (s<<9)|j
    const int s = i >> 9, j = i & 511;
    const float inv = expf(-(float)(2 * j) * (LN_THETA / (float)DMODEL));
    float sn, cs;
    sincosf((float)s * inv, &sn, &cs);
    tab[i] = make_float2(cs, sn);
  }
}

// ---- bf16 MFMA GEMM with COUNTED-VMCNT double buffering (T3+T4 minimum;
// R9-verified win vs __syncthreads).  128x128 tile, 8 waves (4x2, each
// 32x64, acc[2][4] no-spill profile), BK=64, dbuf 64 KB LDS, vmcnt(4)
// steady state, raw s_barrier + sched_barrier(0) fences, XOR chunk swizzle
// staging, XCD-aware block swizzle (both grids %8==0).
// M_QKV epilogue now uses the precomputed RoPE table (no sincosf).
template <int MODE>
__global__ __launch_bounds__(512, 2) void gemm_bf16(const unsigned short* __restrict__ A,
                                                    const unsigned short* __restrict__ Bt,
                                                    void* __restrict__ Cdst_, int N,
                                                    const float2* __restrict__ Rt) {
  __shared__ __align__(16) unsigned short As[2 * 8192];   // 32 KB: dbuf x 2 panels of 128x32
  __shared__ __align__(16) unsigned short Bs[2 * 8192];   // 32 KB

  const int tid = threadIdx.x;
  const int lane = tid & 63, quad = lane >> 4, l16 = lane & 15;
  const int w = tid >> 6, wm = w >> 1, wn = w & 1;   // wm 0..3 (32-row strip), wn 0..1 (64-col half)

  // XCD swizzle: gridDim.x == 32 for both modes.
  const int nwg = gridDim.x * gridDim.y;
  const int bid = blockIdx.x + (blockIdx.y << 5);
  const int swz = (bid & 7) * (nwg >> 3) + (bid >> 3);
  const int row0 = (swz & 31) * 128, col0 = (swz >> 5) * 128;

  const int m0 = tid >> 2;                        // 0..127: staged A-row / B-col
  const int kc0 = (tid & 3) ^ ((m0 >> 1) & 3);    // XOR chunk swizzle (R1-verified)
  const unsigned short* Ag0 = A + (size_t)(row0 + m0) * KDIM + kc0 * 8;
  const unsigned short* Bg0 = Bt + (size_t)(col0 + m0) * KDIM + kc0 * 8;
  unsigned short* Al0 = &As[tid * 8];   // panel-local slot (tid*8 covers one 128x32 panel)
  unsigned short* Bl0 = &Bs[tid * 8];

  // buffer c at +c*8192; panel kh at +kh*4096.  4 gloads per thread per stage.
#define STAGE_GEMM(c, kk)                                        \
  do {                                                           \
    gload_lds16(Ag0 + (kk),      Al0 + (c) * 8192);              \
    gload_lds16(Ag0 + (kk) + 32, Al0 + (c) * 8192 + 4096);       \
    gload_lds16(Bg0 + (kk),      Bl0 + (c) * 8192);              \
    gload_lds16(Bg0 + (kk) + 32, Bl0 + (c) * 8192 + 4096);       \
  } while (0)

  int aoff[2][2], boff[4][2];
#pragma unroll
  for (int mi = 0; mi < 2; ++mi) {
    const int am = wm * 32 + mi * 16 + l16;
    const int sw = quad ^ ((am >> 1) & 3);
#pragma unroll
    for (int kh = 0; kh < 2; ++kh)
      aoff[mi][kh] = kh * 4096 + (((am << 2) | sw) << 3);
  }
#pragma unroll
  for (int ni = 0; ni < 4; ++ni) {
    const int bn = wn * 64 + ni * 16 + l16;
    const int sw = quad ^ ((bn >> 1) & 3);
#pragma unroll
    for (int kh = 0; kh < 2; ++kh)
      boff[ni][kh] = kh * 4096 + (((bn << 2) | sw) << 3);
  }

  f4_t acc[2][4];
#pragma unroll
  for (int mi = 0; mi < 2; ++mi)
#pragma unroll
    for (int ni = 0; ni < 4; ++ni) acc[mi][ni] = (f4_t){0.f, 0.f, 0.f, 0.f};

  STAGE_GEMM(0, 0);
  int cur = 0;
  for (int kb = 0; kb < KDIM; kb += 64) {
    if (kb + 64 < KDIM) {
      STAGE_GEMM(cur ^ 1, kb + 64);                       // 4 new loads in flight
      asm volatile("s_waitcnt vmcnt(4)" ::: "memory");    // buf[cur]'s 4 loads done
    } else {
      asm volatile("s_waitcnt vmcnt(0)" ::: "memory");    // tail: drain
    }
    __builtin_amdgcn_sched_barrier(0);
    __builtin_amdgcn_s_barrier();                         // all waves' buf[cur] staged

    const unsigned short* Asc = As + cur * 8192;
    const unsigned short* Bsc = Bs + cur * 8192;
#pragma unroll
    for (int kh = 0; kh < 2; ++kh) {
      bf8_t af[2], bfr[4];
#pragma unroll
      for (int mi = 0; mi < 2; ++mi) af[mi] = *(const bf8_t*)&Asc[aoff[mi][kh]];
#pragma unroll
      for (int ni = 0; ni < 4; ++ni) bfr[ni] = *(const bf8_t*)&Bsc[boff[ni][kh]];
#pragma unroll
      for (int mi = 0; mi < 2; ++mi)
#pragma unroll
        for (int ni = 0; ni < 4; ++ni)
          acc[mi][ni] = __builtin_amdgcn_mfma_f32_16x16x32_bf16(af[mi], bfr[ni], acc[mi][ni], 0, 0, 0);
    }
    __builtin_amdgcn_sched_barrier(0);
    __builtin_amdgcn_s_barrier();                         // all reads of buf[cur] done
    cur ^= 1;
  }
#undef STAGE_GEMM

  if constexpr (MODE == M_PLAIN) {
    float* out = (float*)Cdst_;
#pragma unroll
    for (int mi = 0; mi < 2; ++mi) {
      const int rowb = row0 + wm * 32 + mi * 16 + quad * 4;
#pragma unroll
      for (int ni = 0; ni < 4; ++ni) {
        const int n = col0 + wn * 64 + ni * 16 + l16;
#pragma unroll
        for (int r = 0; r < 4; ++r)
          out[(size_t)(rowb + r) * N + n] = acc[mi][ni][r];
      }
    }
  } else {  // M_QKV
    unsigned short* Qb = (unsigned short*)Cdst_;
    unsigned short* Kb = Qb + (KB_OFF - QB_OFF);
    unsigned short* Vb = Qb + (VB_OFF - QB_OFF);
#pragma unroll
    for (int ni = 0; ni < 4; ++ni) {
      const int nb = col0 + wn * 64 + ni * 16;   // wave-uniform region selector
      const int n = nb + l16;
      if (nb < 1024) {  // Q + full-D RoPE (table), scale (1/32)*log2(e) folded
        const float sgn = (n & 1) ? 1.f : -1.f;
        const int j = n >> 1;
        const int h = n >> 6, d = n & 63;
#pragma unroll
        for (int mi = 0; mi < 2; ++mi) {
          const int rowb = row0 + wm * 32 + mi * 16 + quad * 4;
#pragma unroll
          for (int r = 0; r < 4; ++r) {
            const int row = rowb + r;
            const int bb = row >> 11, s = row & (SEQ - 1);
            const float v = acc[mi][ni][r];
            const float p = __shfl_xor(v, 1);
            const float2 cssn = Rt[(s << 9) | j];
            const float res = (v * cssn.x + sgn * p * cssn.y) * QSCALE;
            Qb[((size_t)(bb * NH + h) * SEQ + s) * HDIM + d] = f2bf(res);
          }
        }
      } else if (nb < 1280) {  // K + per-head RoPE (table, j = d>>1 < 32)
        const int nk = n - 1024;
        const int hkv = nk >> 6, d = nk & 63;
        const int j = d >> 1;
        const float sgn = (nk & 1) ? 1.f : -1.f;
#pragma unroll
        for (int mi = 0; mi < 2; ++mi) {
          const int rowb = row0 + wm * 32 + mi * 16 + quad * 4;
#pragma unroll
          for (int r = 0; r < 4; ++r) {
            const int row = rowb + r;
            const int bb = row >> 11, s = row & (SEQ - 1);
            const float v = acc[mi][ni][r];
            const float p = __shfl_xor(v, 1);
            const float2 cssn = Rt[(s << 9) | j];
            const float res = v * cssn.x + sgn * p * cssn.y;
            Kb[((size_t)(bb * NKV + hkv) * SEQ + s) * HDIM + d] = f2bf(res);
          }
        }
      } else {  // V, transposed [B][NKV][HDIM][pkey]: keys PERMUTED within each
                // 64-tile: key (cb,quad_k,r) -> pos (cb>>1)*32+quad_k*8+(cb&1)*4+r
                // (matches attn's register-packed PV k-axis; bit-shuffle below)
        const int nv = n - 1280;
        const int hkv = nv >> 6, d = nv & 63;
#pragma unroll
        for (int mi = 0; mi < 2; ++mi) {
          const int s0 = row0 + wm * 32 + mi * 16 + quad * 4;
          const int bb = s0 >> 11, sl = s0 & (SEQ - 1);
          const int st = sl & 63;   // low 2 bits are 0
          const int ps = (sl & ~63) | (st & 0x20) | ((st & 0x0C) << 1) | ((st & 0x10) >> 2);
          us4_t stv = {f2bf(acc[mi][ni][0]), f2bf(acc[mi][ni][1]),
                       f2bf(acc[mi][ni][2]), f2bf(acc[mi][ni][3])};
          *(us4_t*)&Vb[((size_t)(bb * NKV + hkv) * HDIM + d) * SEQ + ps] = stv;
        }
      }
    }
  }
}

// ---- MFMA flash attention v10 (R11, unchanged): 128-q blocks, 4 waves x
// 32q, g=2, NO setprio, XCD-group block swizzle (KV L2-resident: FETCH
// halved, measured).  Attn computes 34.4 GFLOP at ~758 TF -- near its
// structural ceiling; leave it alone.
__global__ __launch_bounds__(256, 4) void attn_fwd(const unsigned short* __restrict__ Q,
                                                   const unsigned short* __restrict__ K,
                                                   const unsigned short* __restrict__ V,
                                                   unsigned short* __restrict__ Ow) {
  __shared__ __align__(16) unsigned short Kt[2 * 4096];  // dbuf x 2 panels [key][d-half], 16 KB
  __shared__ __align__(16) unsigned short Vt[2 * 4096];  // dbuf x 2 panels [d][pkey-half], 16 KB

  // XCD-group swizzle (bijective: 512 blocks, 8 groups of 64).
  const int bid = blockIdx.x + (blockIdx.y << 5);   // x-fast linear dispatch id
  const int grp = bid & 7;                          // -> XCD under round-robin
  const int idx = bid >> 3;                         // 0..63 within group
  const int b   = grp >> 2;
  const int hkv = grp & 3;
  const int h   = hkv * 4 + (idx & 3);
  const int q0  = (idx >> 2) * 128;

  const int tid = threadIdx.x;
  const int w = tid >> 6;
  const int lane = tid & 63;
  const int quad = lane >> 4;
  const int l16 = lane & 15;

  const unsigned short* Qg = Q + ((size_t)(b * NH + h) * SEQ + q0 + w * 32) * HDIM;
  const unsigned short* Kg = K + (size_t)(b * NKV + hkv) * SEQ * HDIM;
  const unsigned short* Vg = V + (size_t)(b * NKV + hkv) * HDIM * SEQ;

  // Q as B-fragments: lane(n=l16 -> q, quad) holds Q[q][d=half*32+quad*8+j]
  bf8_t qb[2][2];
#pragma unroll
  for (int g = 0; g < 2; ++g)
#pragma unroll
    for (int half = 0; half < 2; ++half)
      qb[g][half] = *(const bf8_t*)(Qg + (size_t)(g * 16 + l16) * HDIM + half * 32 + quad * 8);

  f4_t accO[2][4];
#pragma unroll
  for (int g = 0; g < 2; ++g)
#pragma unroll
    for (int d = 0; d < 4; ++d) accO[g][d] = (f4_t){0.f, 0.f, 0.f, 0.f};
  float accLs[2] = {0.f, 0.f};

  // fragment slot swizzle (row = cb*16+l16 or db*16+l16; (row>>1)&3 = (l16>>1)&3)
  const int sw8 = (quad ^ ((l16 >> 1) & 3)) << 3;   // element offset of 16B slot

  // staging: thread t -> row t>>2, slot t&3, global chunk (t&3)^((row>>1)&3)
  const int skey = tid >> 2;
  const int gc = ((tid & 3) ^ ((tid >> 3) & 3)) << 3;
  const unsigned short* KgA = Kg + (size_t)skey * HDIM + gc;
  const unsigned short* VgA = Vg + (size_t)skey * SEQ + gc;

#define STAGE_ATTN(c, kk)                                                          \
  do {                                                                             \
    gload_lds16(KgA + (size_t)(kk) * HDIM,      &Kt[(c) * 4096 + tid * 8]);        \
    gload_lds16(KgA + (size_t)(kk) * HDIM + 32, &Kt[(c) * 4096 + tid * 8 + 2048]); \
    gload_lds16(VgA + (kk),      &Vt[(c) * 4096 + tid * 8]);                       \
    gload_lds16(VgA + (kk) + 32, &Vt[(c) * 4096 + tid * 8 + 2048]);                \
  } while (0)

  STAGE_ATTN(0, 0);
  __syncthreads();
  int cur = 0;
  for (int k0 = 0; k0 < SEQ; k0 += 64) {
    if (k0 + 64 < SEQ) STAGE_ATTN(cur ^ 1, k0 + 64);   // prefetch next tile

    const unsigned short* Ktc = Kt + cur * 4096;
    const unsigned short* Vtc = Vt + cur * 4096;

    // S^T = K Q^T per 16-key block; P = exp2(S^T) packed straight into
    // PV A-fragments (permuted k-axis; v_cvt_pk_bf16_f32)
    union { bf8_t bf; unsigned int dw[4]; } pa[2][2];
#pragma unroll
    for (int cb = 0; cb < 4; ++cb) {
      const int koff = (cb * 16 + l16) * 32 + sw8;
      bf8_t kf0 = *(const bf8_t*)&Ktc[koff];
      bf8_t kf1 = *(const bf8_t*)&Ktc[koff + 2048];
#pragma unroll
      for (int g = 0; g < 2; ++g) {
        f4_t s = (f4_t){0.f, 0.f, 0.f, 0.f};
        s = __builtin_amdgcn_mfma_f32_16x16x32_bf16(kf0, qb[g][0], s, 0, 0, 0);
        s = __builtin_amdgcn_mfma_f32_16x16x32_bf16(kf1, qb[g][1], s, 0, 0, 0);
        const float p0 = fexp2(s[0]), p1 = fexp2(s[1]);
        const float p2 = fexp2(s[2]), p3 = fexp2(s[3]);
        accLs[g] += (p0 + p1) + (p2 + p3);
        unsigned int w0, w1;
        asm("v_cvt_pk_bf16_f32 %0, %1, %2" : "=v"(w0) : "v"(p0), "v"(p1));
        asm("v_cvt_pk_bf16_f32 %0, %1, %2" : "=v"(w1) : "v"(p2), "v"(p3));
        pa[g][cb >> 1].dw[(cb & 1) * 2 + 0] = w0;
        pa[g][cb >> 1].dw[(cb & 1) * 2 + 1] = w1;
      }
    }

    // O += P V ; V B-frag = one b128 (permuted global key order matches pa)
#pragma unroll
    for (int db = 0; db < 4; ++db) {
      const int voff = (db * 16 + l16) * 32 + sw8;
      bf8_t vf0 = *(const bf8_t*)&Vtc[voff];
      bf8_t vf1 = *(const bf8_t*)&Vtc[voff + 2048];
#pragma unroll
      for (int g = 0; g < 2; ++g) {
        accO[g][db] = __builtin_amdgcn_mfma_f32_16x16x32_bf16(pa[g][0].bf, vf0, accO[g][db], 0, 0, 0);
        accO[g][db] = __builtin_amdgcn_mfma_f32_16x16x32_bf16(pa[g][1].bf, vf1, accO[g][db], 0, 0, 0);
      }
    }

    __syncthreads();   // drains prefetch vmcnt AFTER compute (latency hidden)
    cur ^= 1;
  }
#undef STAGE_ATTN

  // L: per-lane partials cover keys {quad*4+r} for q=l16 -> reduce across quads.
  // After the xor-reduce every lane holds the FULL L for q = g*16 + l16.
#pragma unroll
  for (int g = 0; g < 2; ++g) {
    accLs[g] += __shfl_xor(accLs[g], 16);
    accLs[g] += __shfl_xor(accLs[g], 32);
  }
  const float il0 = 1.0f / accLs[0];
  const float il1 = 1.0f / accLs[1];

  // write normalized bf16 straight into Owb[b*SEQ+q][h*64+d]
#pragma unroll
  for (int g = 0; g < 2; ++g)
#pragma unroll
    for (int r = 0; r < 4; ++r) {
      // L-reciprocal for this fragment row (q-row quad*4+r) lives at lane l16=quad*4+r
      const float ilr = __shfl(g ? il1 : il0, quad * 4 + r);
      const int q = q0 + w * 32 + g * 16 + quad * 4 + r;
      unsigned short* op = Ow + (((size_t)b * SEQ + q) * NH + h) * HDIM;
#pragma unroll
      for (int db = 0; db < 4; ++db)
        op[db * 16 + l16] = f2bf(accO[g][db][r] * ilr);
    }
}

extern "C" void kernel_launch(void* const* d_in, const int* in_sizes, int n_in,
                              void* d_out, int out_size, void* d_ws, size_t ws_size,
                              hipStream_t stream) {
  (void)in_sizes; (void)n_in; (void)out_size; (void)ws_size;
  const float* x  = (const float*)d_in[0];
  const float* Wq = (const float*)d_in[1];
  const float* Wk = (const float*)d_in[2];
  const float* Wv = (const float*)d_in[3];
  const float* Wo = (const float*)d_in[4];
  float* out = (float*)d_out;

  // ws layout (bf16 units) + RoPE table (float2, 8 MB) at the end.
  unsigned short* Qb    = (unsigned short*)d_ws;          // 4194304
  unsigned short* Kb    = Qb + 4194304;                   // 1048576
  unsigned short* Vb    = Kb + 1048576;                   // 1048576
  unsigned short* Owb   = Vb + 1048576;                   // 4194304
  unsigned short* xb    = Owb + 4194304;                  // 4194304
  unsigned short* Wqkvt = xb + 4194304;                   // 1572864 (Q|K|V rows)
  unsigned short* Wot   = Wqkvt + 1572864;                // 1048576
  float2* Rt = (float2*)(Wot + 1048576);                  // 1048576 float2 = 8 MB

  prep<<<dim3(9216), dim3(256), 0, stream>>>(x, Wq, Wk, Wv, Wo, xb, Wqkvt, Wot, Rt);

  gemm_bf16<M_QKV><<<dim3(32, 12), dim3(512), 0, stream>>>(xb, Wqkvt, Qb, 1536, Rt);
  attn_fwd<<<dim3(32, 16), dim3(256), 0, stream>>>(Qb, Kb, Vb, Owb);
  gemm_bf16<M_PLAIN><<<dim3(32, 8), dim3(512), 0, stream>>>(Owb, Wot, out, DMODEL, nullptr);
}

// Round 13
// 160.325 us; speedup vs baseline: 1.0451x; 1.0156x over previous
//
#include <hip/hip_runtime.h>
#include <math.h>

#define BATCH 2
#define SEQ   2048
#define DMODEL 1024
#define KDIM  1024
#define NH    16
#define HDIM  64
#define GRP   4
#define NKV   4   // NH / GRP

enum { M_PLAIN = 0, M_QKV = 1 };

// ln(10000)
#define LN_THETA 9.210340371976184f
// 0.03125 * log2(e): Q carries the 1/sqrt(D) scale AND the exp->exp2 conversion
#define QSCALE 0.04508422002778f

typedef short bf8_t __attribute__((ext_vector_type(8)));
typedef float f4_t __attribute__((ext_vector_type(4)));
typedef unsigned short us4_t __attribute__((ext_vector_type(4)));
typedef unsigned short us8_t __attribute__((ext_vector_type(8)));

// ws element offsets (bf16 units) -- Qb/Kb/Vb must stay contiguous in this order
#define QB_OFF 0
#define KB_OFF 4194304
#define VB_OFF (4194304 + 1048576)

__device__ __forceinline__ unsigned short f2bf(float f) {
  unsigned int u = __float_as_uint(f);
  u += 0x7fffu + ((u >> 16) & 1u);   // RNE
  return (unsigned short)(u >> 16);
}

__device__ __forceinline__ float fexp2(float x) {
#if __has_builtin(__builtin_amdgcn_exp2f)
  return __builtin_amdgcn_exp2f(x);
#else
  return exp2f(x);
#endif
}

__device__ __forceinline__ void gload_lds16(const void* g, void* l) {
  typedef __attribute__((address_space(1))) unsigned int gu32;
  typedef __attribute__((address_space(3))) unsigned int lu32;
  __builtin_amdgcn_global_load_lds((const gu32*)g, (lu32*)l, 16, 0, 0);
}

// ---- fused prep: ONE launch does (a) x fp32->bf16, (b) all 4 weight
// transposes, (c) RoPE cos/sin table.  Flat grid of 9216 blocks, ranges
// route.  tab[(s<<9)|j] = {cos(s*inv_j), sin(s*inv_j)}; Q uses j = n>>1,
// K uses j = d>>1 (<32) -- one table covers both.
__global__ __launch_bounds__(256) void prep(const float* __restrict__ x,
                                            const float* __restrict__ W0,
                                            const float* __restrict__ W1,
                                            const float* __restrict__ W2,
                                            const float* __restrict__ W3,
                                            unsigned short* __restrict__ xb,
                                            unsigned short* __restrict__ Wqkvt,
                                            unsigned short* __restrict__ Wot,
                                            float2* __restrict__ tab) {
  __shared__ unsigned short T[64][72];
  const int blk = blockIdx.x;
  const int t = threadIdx.x;

  if (blk < 4096) {            // ---- conv_x: 4096 blocks
    const int i = blk * 256 + t;
    float4 v = ((const float4*)x)[i];
    us4_t o = {f2bf(v.x), f2bf(v.y), f2bf(v.z), f2bf(v.w)};
    ((us4_t*)xb)[i] = o;
  } else if (blk < 5120) {     // ---- convT_all: 1024 blocks (16 x 16 x 4)
    const int flat = blk - 4096;
    const int bx = flat & 15, by = (flat >> 4) & 15, bz = flat >> 8;
    const float* W; unsigned short* out; int N, rowoff;
    switch (bz) {
      case 0: W = W0; out = Wqkvt; N = 1024; rowoff = 0;    break;
      case 1: W = W1; out = Wqkvt; N = 256;  rowoff = 1024; break;
      case 2: W = W2; out = Wqkvt; N = 256;  rowoff = 1280; break;
      default: W = W3; out = Wot;  N = 1024; rowoff = 0;    break;
    }
    const int n0 = bx * 64;
    if (n0 >= N) return;
    const int k0 = by * 64;
    const int kr = t >> 4, n4 = (t & 15) * 4;
#pragma unroll
    for (int i = 0; i < 4; ++i) {
      const int k = kr + i * 16;
      float4 v = *(const float4*)&W[(size_t)(k0 + k) * N + n0 + n4];
      T[n4 + 0][k] = f2bf(v.x);
      T[n4 + 1][k] = f2bf(v.y);
      T[n4 + 2][k] = f2bf(v.z);
      T[n4 + 3][k] = f2bf(v.w);
    }
    __syncthreads();
#pragma unroll
    for (int i = 0; i < 2; ++i) {
      const int c = t + i * 256;
      const int n = c >> 3, kc = (c & 7) * 8;
      us8_t v = *(const us8_t*)&T[n][kc];
      *(us8_t*)&out[(size_t)(rowoff + n0 + n) * KDIM + k0 + kc] = v;
    }
  } else {                     // ---- RoPE table: 4096 blocks, 1M entries
    const int i = (blk - 5120) * 256 + t;     // (s<<9)|j
    const int s = i >> 9, j = i & 511;
    const float inv = expf(-(float)(2 * j) * (LN_THETA / (float)DMODEL));
    float sn, cs;
    sincosf((float)s * inv, &sn, &cs);
    tab[i] = make_float2(cs, sn);
  }
}

// ---- bf16 MFMA GEMM with COUNTED-VMCNT double buffering (T3+T4 minimum;
// R9-verified win vs __syncthreads).  128x128 tile, 8 waves (4x2, each
// 32x64, acc[2][4] no-spill profile), BK=64, dbuf 64 KB LDS, vmcnt(4)
// steady state, raw s_barrier + sched_barrier(0) fences, XOR chunk swizzle
// staging, XCD-aware block swizzle (both grids %8==0).
// M_QKV epilogue uses the precomputed RoPE table (no sincosf).
template <int MODE>
__global__ __launch_bounds__(512, 2) void gemm_bf16(const unsigned short* __restrict__ A,
                                                    const unsigned short* __restrict__ Bt,
                                                    void* __restrict__ Cdst_, int N,
                                                    const float2* __restrict__ Rt) {
  __shared__ __align__(16) unsigned short As[2 * 8192];   // 32 KB: dbuf x 2 panels of 128x32
  __shared__ __align__(16) unsigned short Bs[2 * 8192];   // 32 KB

  const int tid = threadIdx.x;
  const int lane = tid & 63, quad = lane >> 4, l16 = lane & 15;
  const int w = tid >> 6, wm = w >> 1, wn = w & 1;   // wm 0..3 (32-row strip), wn 0..1 (64-col half)

  // XCD swizzle: gridDim.x == 32 for both modes.
  const int nwg = gridDim.x * gridDim.y;
  const int bid = blockIdx.x + (blockIdx.y << 5);
  const int swz = (bid & 7) * (nwg >> 3) + (bid >> 3);
  const int row0 = (swz & 31) * 128, col0 = (swz >> 5) * 128;

  const int m0 = tid >> 2;                        // 0..127: staged A-row / B-col
  const int kc0 = (tid & 3) ^ ((m0 >> 1) & 3);    // XOR chunk swizzle (R1-verified)
  const unsigned short* Ag0 = A + (size_t)(row0 + m0) * KDIM + kc0 * 8;
  const unsigned short* Bg0 = Bt + (size_t)(col0 + m0) * KDIM + kc0 * 8;
  unsigned short* Al0 = &As[tid * 8];   // panel-local slot (tid*8 covers one 128x32 panel)
  unsigned short* Bl0 = &Bs[tid * 8];

  // buffer c at +c*8192; panel kh at +kh*4096.  4 gloads per thread per stage.
#define STAGE_GEMM(c, kk)                                        \
  do {                                                           \
    gload_lds16(Ag0 + (kk),      Al0 + (c) * 8192);              \
    gload_lds16(Ag0 + (kk) + 32, Al0 + (c) * 8192 + 4096);       \
    gload_lds16(Bg0 + (kk),      Bl0 + (c) * 8192);              \
    gload_lds16(Bg0 + (kk) + 32, Bl0 + (c) * 8192 + 4096);       \
  } while (0)

  int aoff[2][2], boff[4][2];
#pragma unroll
  for (int mi = 0; mi < 2; ++mi) {
    const int am = wm * 32 + mi * 16 + l16;
    const int sw = quad ^ ((am >> 1) & 3);
#pragma unroll
    for (int kh = 0; kh < 2; ++kh)
      aoff[mi][kh] = kh * 4096 + (((am << 2) | sw) << 3);
  }
#pragma unroll
  for (int ni = 0; ni < 4; ++ni) {
    const int bn = wn * 64 + ni * 16 + l16;
    const int sw = quad ^ ((bn >> 1) & 3);
#pragma unroll
    for (int kh = 0; kh < 2; ++kh)
      boff[ni][kh] = kh * 4096 + (((bn << 2) | sw) << 3);
  }

  f4_t acc[2][4];
#pragma unroll
  for (int mi = 0; mi < 2; ++mi)
#pragma unroll
    for (int ni = 0; ni < 4; ++ni) acc[mi][ni] = (f4_t){0.f, 0.f, 0.f, 0.f};

  STAGE_GEMM(0, 0);
  int cur = 0;
  for (int kb = 0; kb < KDIM; kb += 64) {
    if (kb + 64 < KDIM) {
      STAGE_GEMM(cur ^ 1, kb + 64);                       // 4 new loads in flight
      asm volatile("s_waitcnt vmcnt(4)" ::: "memory");    // buf[cur]'s 4 loads done
    } else {
      asm volatile("s_waitcnt vmcnt(0)" ::: "memory");    // tail: drain
    }
    __builtin_amdgcn_sched_barrier(0);
    __builtin_amdgcn_s_barrier();                         // all waves' buf[cur] staged

    const unsigned short* Asc = As + cur * 8192;
    const unsigned short* Bsc = Bs + cur * 8192;
#pragma unroll
    for (int kh = 0; kh < 2; ++kh) {
      bf8_t af[2], bfr[4];
#pragma unroll
      for (int mi = 0; mi < 2; ++mi) af[mi] = *(const bf8_t*)&Asc[aoff[mi][kh]];
#pragma unroll
      for (int ni = 0; ni < 4; ++ni) bfr[ni] = *(const bf8_t*)&Bsc[boff[ni][kh]];
#pragma unroll
      for (int mi = 0; mi < 2; ++mi)
#pragma unroll
        for (int ni = 0; ni < 4; ++ni)
          acc[mi][ni] = __builtin_amdgcn_mfma_f32_16x16x32_bf16(af[mi], bfr[ni], acc[mi][ni], 0, 0, 0);
    }
    __builtin_amdgcn_sched_barrier(0);
    __builtin_amdgcn_s_barrier();                         // all reads of buf[cur] done
    cur ^= 1;
  }
#undef STAGE_GEMM

  if constexpr (MODE == M_PLAIN) {
    float* out = (float*)Cdst_;
#pragma unroll
    for (int mi = 0; mi < 2; ++mi) {
      const int rowb = row0 + wm * 32 + mi * 16 + quad * 4;
#pragma unroll
      for (int ni = 0; ni < 4; ++ni) {
        const int n = col0 + wn * 64 + ni * 16 + l16;
#pragma unroll
        for (int r = 0; r < 4; ++r)
          out[(size_t)(rowb + r) * N + n] = acc[mi][ni][r];
      }
    }
  } else {  // M_QKV
    unsigned short* Qb = (unsigned short*)Cdst_;
    unsigned short* Kb = Qb + (KB_OFF - QB_OFF);
    unsigned short* Vb = Qb + (VB_OFF - QB_OFF);
#pragma unroll
    for (int ni = 0; ni < 4; ++ni) {
      const int nb = col0 + wn * 64 + ni * 16;   // wave-uniform region selector
      const int n = nb + l16;
      if (nb < 1024) {  // Q + full-D RoPE (table), scale (1/32)*log2(e) folded
        const float sgn = (n & 1) ? 1.f : -1.f;
        const int j = n >> 1;
        const int h = n >> 6, d = n & 63;
#pragma unroll
        for (int mi = 0; mi < 2; ++mi) {
          const int rowb = row0 + wm * 32 + mi * 16 + quad * 4;
#pragma unroll
          for (int r = 0; r < 4; ++r) {
            const int row = rowb + r;
            const int bb = row >> 11, s = row & (SEQ - 1);
            const float v = acc[mi][ni][r];
            const float p = __shfl_xor(v, 1);
            const float2 cssn = Rt[(s << 9) | j];
            const float res = (v * cssn.x + sgn * p * cssn.y) * QSCALE;
            Qb[((size_t)(bb * NH + h) * SEQ + s) * HDIM + d] = f2bf(res);
          }
        }
      } else if (nb < 1280) {  // K + per-head RoPE (table, j = d>>1 < 32)
        const int nk = n - 1024;
        const int hkv = nk >> 6, d = nk & 63;
        const int j = d >> 1;
        const float sgn = (nk & 1) ? 1.f : -1.f;
#pragma unroll
        for (int mi = 0; mi < 2; ++mi) {
          const int rowb = row0 + wm * 32 + mi * 16 + quad * 4;
#pragma unroll
          for (int r = 0; r < 4; ++r) {
            const int row = rowb + r;
            const int bb = row >> 11, s = row & (SEQ - 1);
            const float v = acc[mi][ni][r];
            const float p = __shfl_xor(v, 1);
            const float2 cssn = Rt[(s << 9) | j];
            const float res = v * cssn.x + sgn * p * cssn.y;
            Kb[((size_t)(bb * NKV + hkv) * SEQ + s) * HDIM + d] = f2bf(res);
          }
        }
      } else {  // V, transposed [B][NKV][HDIM][pkey]: keys PERMUTED within each
                // 64-tile: key (cb,quad_k,r) -> pos (cb>>1)*32+quad_k*8+(cb&1)*4+r
                // (matches attn's register-packed PV k-axis; bit-shuffle below)
        const int nv = n - 1280;
        const int hkv = nv >> 6, d = nv & 63;
#pragma unroll
        for (int mi = 0; mi < 2; ++mi) {
          const int s0 = row0 + wm * 32 + mi * 16 + quad * 4;
          const int bb = s0 >> 11, sl = s0 & (SEQ - 1);
          const int st = sl & 63;   // low 2 bits are 0
          const int ps = (sl & ~63) | (st & 0x20) | ((st & 0x0C) << 1) | ((st & 0x10) >> 2);
          us4_t stv = {f2bf(acc[mi][ni][0]), f2bf(acc[mi][ni][1]),
                       f2bf(acc[mi][ni][2]), f2bf(acc[mi][ni][3])};
          *(us4_t*)&Vb[((size_t)(bb * NKV + hkv) * HDIM + d) * SEQ + ps] = stv;
        }
      }
    }
  }
}

// ---- MFMA flash attention v11: v10 + COUNTED-VMCNT loop (T4, the R9
// gemm-proven lever, now applied to attn).  The old __syncthreads per
// 64-key tile drained the 4 just-issued prefetch loads every iteration
// (32 x exposed L2 latency).  New loop: STAGE(next) -> vmcnt(4) (only the
// CURRENT tile's 4 loads must be done) -> s_barrier -> compute -> s_barrier.
// Buffer safety identical to the gemm: reads of buf[c] complete before the
// end-of-iteration barrier; buf[c] is restaged only after that barrier.
// 128-q blocks, 4 waves x 32q, g=2, NO setprio, XCD-group swizzle.
__global__ __launch_bounds__(256, 4) void attn_fwd(const unsigned short* __restrict__ Q,
                                                   const unsigned short* __restrict__ K,
                                                   const unsigned short* __restrict__ V,
                                                   unsigned short* __restrict__ Ow) {
  __shared__ __align__(16) unsigned short Kt[2 * 4096];  // dbuf x 2 panels [key][d-half], 16 KB
  __shared__ __align__(16) unsigned short Vt[2 * 4096];  // dbuf x 2 panels [d][pkey-half], 16 KB

  // XCD-group swizzle (bijective: 512 blocks, 8 groups of 64).
  const int bid = blockIdx.x + (blockIdx.y << 5);   // x-fast linear dispatch id
  const int grp = bid & 7;                          // -> XCD under round-robin
  const int idx = bid >> 3;                         // 0..63 within group
  const int b   = grp >> 2;
  const int hkv = grp & 3;
  const int h   = hkv * 4 + (idx & 3);
  const int q0  = (idx >> 2) * 128;

  const int tid = threadIdx.x;
  const int w = tid >> 6;
  const int lane = tid & 63;
  const int quad = lane >> 4;
  const int l16 = lane & 15;

  const unsigned short* Qg = Q + ((size_t)(b * NH + h) * SEQ + q0 + w * 32) * HDIM;
  const unsigned short* Kg = K + (size_t)(b * NKV + hkv) * SEQ * HDIM;
  const unsigned short* Vg = V + (size_t)(b * NKV + hkv) * HDIM * SEQ;

  // Q as B-fragments: lane(n=l16 -> q, quad) holds Q[q][d=half*32+quad*8+j]
  bf8_t qb[2][2];
#pragma unroll
  for (int g = 0; g < 2; ++g)
#pragma unroll
    for (int half = 0; half < 2; ++half)
      qb[g][half] = *(const bf8_t*)(Qg + (size_t)(g * 16 + l16) * HDIM + half * 32 + quad * 8);

  f4_t accO[2][4];
#pragma unroll
  for (int g = 0; g < 2; ++g)
#pragma unroll
    for (int d = 0; d < 4; ++d) accO[g][d] = (f4_t){0.f, 0.f, 0.f, 0.f};
  float accLs[2] = {0.f, 0.f};

  // fragment slot swizzle (row = cb*16+l16 or db*16+l16; (row>>1)&3 = (l16>>1)&3)
  const int sw8 = (quad ^ ((l16 >> 1) & 3)) << 3;   // element offset of 16B slot

  // staging: thread t -> row t>>2, slot t&3, global chunk (t&3)^((row>>1)&3)
  const int skey = tid >> 2;
  const int gc = ((tid & 3) ^ ((tid >> 3) & 3)) << 3;
  const unsigned short* KgA = Kg + (size_t)skey * HDIM + gc;
  const unsigned short* VgA = Vg + (size_t)skey * SEQ + gc;

#define STAGE_ATTN(c, kk)                                                          \
  do {                                                                             \
    gload_lds16(KgA + (size_t)(kk) * HDIM,      &Kt[(c) * 4096 + tid * 8]);        \
    gload_lds16(KgA + (size_t)(kk) * HDIM + 32, &Kt[(c) * 4096 + tid * 8 + 2048]); \
    gload_lds16(VgA + (kk),      &Vt[(c) * 4096 + tid * 8]);                       \
    gload_lds16(VgA + (kk) + 32, &Vt[(c) * 4096 + tid * 8 + 2048]);                \
  } while (0)

  STAGE_ATTN(0, 0);
  int cur = 0;
  for (int k0 = 0; k0 < SEQ; k0 += 64) {
    if (k0 + 64 < SEQ) {
      STAGE_ATTN(cur ^ 1, k0 + 64);                       // 4 new loads in flight
      asm volatile("s_waitcnt vmcnt(4)" ::: "memory");    // buf[cur]'s 4 loads done
    } else {
      asm volatile("s_waitcnt vmcnt(0)" ::: "memory");    // tail: drain
    }
    __builtin_amdgcn_sched_barrier(0);
    __builtin_amdgcn_s_barrier();                         // all waves' buf[cur] staged

    const unsigned short* Ktc = Kt + cur * 4096;
    const unsigned short* Vtc = Vt + cur * 4096;

    // S^T = K Q^T per 16-key block; P = exp2(S^T) packed straight into
    // PV A-fragments (permuted k-axis; v_cvt_pk_bf16_f32)
    union { bf8_t bf; unsigned int dw[4]; } pa[2][2];
#pragma unroll
    for (int cb = 0; cb < 4; ++cb) {
      const int koff = (cb * 16 + l16) * 32 + sw8;
      bf8_t kf0 = *(const bf8_t*)&Ktc[koff];
      bf8_t kf1 = *(const bf8_t*)&Ktc[koff + 2048];
#pragma unroll
      for (int g = 0; g < 2; ++g) {
        f4_t s = (f4_t){0.f, 0.f, 0.f, 0.f};
        s = __builtin_amdgcn_mfma_f32_16x16x32_bf16(kf0, qb[g][0], s, 0, 0, 0);
        s = __builtin_amdgcn_mfma_f32_16x16x32_bf16(kf1, qb[g][1], s, 0, 0, 0);
        const float p0 = fexp2(s[0]), p1 = fexp2(s[1]);
        const float p2 = fexp2(s[2]), p3 = fexp2(s[3]);
        accLs[g] += (p0 + p1) + (p2 + p3);
        unsigned int w0, w1;
        asm("v_cvt_pk_bf16_f32 %0, %1, %2" : "=v"(w0) : "v"(p0), "v"(p1));
        asm("v_cvt_pk_bf16_f32 %0, %1, %2" : "=v"(w1) : "v"(p2), "v"(p3));
        pa[g][cb >> 1].dw[(cb & 1) * 2 + 0] = w0;
        pa[g][cb >> 1].dw[(cb & 1) * 2 + 1] = w1;
      }
    }

    // O += P V ; V B-frag = one b128 (permuted global key order matches pa)
#pragma unroll
    for (int db = 0; db < 4; ++db) {
      const int voff = (db * 16 + l16) * 32 + sw8;
      bf8_t vf0 = *(const bf8_t*)&Vtc[voff];
      bf8_t vf1 = *(const bf8_t*)&Vtc[voff + 2048];
#pragma unroll
      for (int g = 0; g < 2; ++g) {
        accO[g][db] = __builtin_amdgcn_mfma_f32_16x16x32_bf16(pa[g][0].bf, vf0, accO[g][db], 0, 0, 0);
        accO[g][db] = __builtin_amdgcn_mfma_f32_16x16x32_bf16(pa[g][1].bf, vf1, accO[g][db], 0, 0, 0);
      }
    }

    __builtin_amdgcn_sched_barrier(0);
    __builtin_amdgcn_s_barrier();                         // all reads of buf[cur] done
    cur ^= 1;
  }
#undef STAGE_ATTN

  // L: per-lane partials cover keys {quad*4+r} for q=l16 -> reduce across quads.
  // After the xor-reduce every lane holds the FULL L for q = g*16 + l16.
#pragma unroll
  for (int g = 0; g < 2; ++g) {
    accLs[g] += __shfl_xor(accLs[g], 16);
    accLs[g] += __shfl_xor(accLs[g], 32);
  }
  const float il0 = 1.0f / accLs[0];
  const float il1 = 1.0f / accLs[1];

  // write normalized bf16 straight into Owb[b*SEQ+q][h*64+d]
#pragma unroll
  for (int g = 0; g < 2; ++g)
#pragma unroll
    for (int r = 0; r < 4; ++r) {
      // L-reciprocal for this fragment row (q-row quad*4+r) lives at lane l16=quad*4+r
      const float ilr = __shfl(g ? il1 : il0, quad * 4 + r);
      const int q = q0 + w * 32 + g * 16 + quad * 4 + r;
      unsigned short* op = Ow + (((size_t)b * SEQ + q) * NH + h) * HDIM;
#pragma unroll
      for (int db = 0; db < 4; ++db)
        op[db * 16 + l16] = f2bf(accO[g][db][r] * ilr);
    }
}

extern "C" void kernel_launch(void* const* d_in, const int* in_sizes, int n_in,
                              void* d_out, int out_size, void* d_ws, size_t ws_size,
                              hipStream_t stream) {
  (void)in_sizes; (void)n_in; (void)out_size; (void)ws_size;
  const float* x  = (const float*)d_in[0];
  const float* Wq = (const float*)d_in[1];
  const float* Wk = (const float*)d_in[2];
  const float* Wv = (const float*)d_in[3];
  const float* Wo = (const float*)d_in[4];
  float* out = (float*)d_out;

  // ws layout (bf16 units) + RoPE table (float2, 8 MB) at the end.
  unsigned short* Qb    = (unsigned short*)d_ws;          // 4194304
  unsigned short* Kb    = Qb + 4194304;                   // 1048576
  unsigned short* Vb    = Kb + 1048576;                   // 1048576
  unsigned short* Owb   = Vb + 1048576;                   // 4194304
  unsigned short* xb    = Owb + 4194304;                  // 4194304
  unsigned short* Wqkvt = xb + 4194304;                   // 1572864 (Q|K|V rows)
  unsigned short* Wot   = Wqkvt + 1572864;                // 1048576
  float2* Rt = (float2*)(Wot + 1048576);                  // 1048576 float2 = 8 MB

  prep<<<dim3(9216), dim3(256), 0, stream>>>(x, Wq, Wk, Wv, Wo, xb, Wqkvt, Wot, Rt);

  gemm_bf16<M_QKV><<<dim3(32, 12), dim3(512), 0, stream>>>(xb, Wqkvt, Qb, 1536, Rt);
  attn_fwd<<<dim3(32, 16), dim3(256), 0, stream>>>(Qb, Kb, Vb, Owb);
  gemm_bf16<M_PLAIN><<<dim3(32, 8), dim3(512), 0, stream>>>(Owb, Wot, out, DMODEL, nullptr);
}